// Round 1
// 459.274 us; speedup vs baseline: 1.0824x; 1.0824x over previous
//
#include <hip/hip_runtime.h>

// Problem constants
#define BB 16
#define TT 1024
#define DD 1024
#define HH 1024
#define NN 3072            // 3H
#define KK 2048            // 2D (two conv taps)
#define MM (BB * TT)       // 16384
#define TP (TT + 1)        // padded time rows in xpad (row 0 = zeros)
#define NCH 32             // scan chunks
#define TC  32             // steps per chunk (NCH*TC == TT)
#define PLANE (1u << 24)   // 16M elements per gate plane ( = BB*HH*TT )

typedef __attribute__((ext_vector_type(8))) short short8;   // 8 x bf16
typedef __attribute__((ext_vector_type(4))) float float4v;  // MFMA acc

__device__ __forceinline__ unsigned short f2bf(float f) {
    unsigned int u = __float_as_uint(f);
    u += 0x7fffu + ((u >> 16) & 1u);   // round-to-nearest-even
    return (unsigned short)(u >> 16);
}
__device__ __forceinline__ float bf2f(unsigned short s) {
    return __uint_as_float(((unsigned int)s) << 16);
}

// async global->LDS, 16B per lane; LDS dest semantics: wave-uniform base + lane*16
__device__ __forceinline__ void gload_lds16(const unsigned short* g, unsigned short* l) {
    __builtin_amdgcn_global_load_lds(
        (const __attribute__((address_space(1))) unsigned int*)(g),
        (__attribute__((address_space(3))) unsigned int*)(l),
        16, 0, 0);
}

// ---------------- pack x: fp32 [B,T,D] -> bf16 xpad [B, T+1, D], row 0 zero ----------------
__global__ __launch_bounds__(256) void pack_x_kernel(const float* __restrict__ x,
                                                     unsigned short* __restrict__ xpad) {
    int i = blockIdx.x * 256 + threadIdx.x;          // one float4 group
    int total = BB * TP * (DD / 4);
    if (i >= total) return;
    int d4  = i & (DD / 4 - 1);
    int row = i >> 8;                                // [0, B*TP)
    int b  = row / TP;
    int tp = row - b * TP;
    float4 v = make_float4(0.f, 0.f, 0.f, 0.f);
    if (tp > 0)
        v = ((const float4*)x)[(((size_t)(b * TT + tp - 1)) << 8) + d4];
    ushort4 r4;
    r4.x = f2bf(v.x); r4.y = f2bf(v.y); r4.z = f2bf(v.z); r4.w = f2bf(v.w);
    *(ushort4*)(xpad + (((size_t)row) << 10) + (d4 << 2)) = r4;
}

// ---------------- pack w: fp32 [3H, D, 2] -> bf16 Bt [N=3072][K=2048] (B^T layout) ----------
__global__ __launch_bounds__(256) void pack_w_kernel(const float* __restrict__ w,
                                                     unsigned short* __restrict__ Bt) {
    int i = blockIdx.x * 256 + threadIdx.x;          // n*1024 + d
    if (i >= NN * DD) return;
    int n = i >> 10, d = i & 1023;
    float2 v = ((const float2*)w)[i];                // (w[n,d,0], w[n,d,1])
    Bt[(size_t)n * KK + d]       = f2bf(v.x);        // tap0 at k = d
    Bt[(size_t)n * KK + DD + d]  = f2bf(v.y);        // tap1 at k = 1024 + d
}

// ---------------- GEMM: gates = A * W^T, fused bias + activation ---------------------------
// 256x256 tile, BK=64, 512 threads (8 waves as 2M x 4N, 128x64 per wave).
// Double-buffered 128KB LDS; full-tile prefetch lead: all 8 global_load_lds for tile j+1
// issued at tile j phase 0, single vmcnt(0) at end of phase 3 (~3000cy after issue -> ~free).
// 4 phases per K-tile: {ds_read A-quadrant; barrier; setprio1; 16 MFMA; setprio0; barrier}.
// LDS chunk-swizzle: physical 16B chunk pc at row r holds logical chunk pc^(r&7); applied on
// the global SOURCE address (gload_lds writes linearly) and mirrored on ds_read addresses.

#define VMCNT0 asm volatile("s_waitcnt vmcnt(0)" ::: "memory")
#define BARRIER_F() do { __builtin_amdgcn_s_barrier(); asm volatile("" ::: "memory"); } while (0)

#define STAGE_TILE(ASN, BSN, KT) do {                                          \
    const int tap_ = (KT) >> 4;                                                \
    const size_t aoff_ = aSrc + (((size_t)tap_) << 10) + (((KT) & 15) << 6);   \
    const size_t boff_ = bSrc + (((size_t)(KT)) << 6);                         \
    gload_lds16(xpad + aoff_,                 (ASN) + ldsStage);               \
    gload_lds16(xpad + aoff_ + (64u << 10),   (ASN) + ldsStage + 4096);        \
    gload_lds16(xpad + aoff_ + (128u << 10),  (ASN) + ldsStage + 8192);        \
    gload_lds16(xpad + aoff_ + (192u << 10),  (ASN) + ldsStage + 12288);       \
    gload_lds16(Btw + boff_,                  (BSN) + ldsStage);               \
    gload_lds16(Btw + boff_ + (64u << 11),    (BSN) + ldsStage + 4096);        \
    gload_lds16(Btw + boff_ + (128u << 11),   (BSN) + ldsStage + 8192);        \
    gload_lds16(Btw + boff_ + (192u << 11),   (BSN) + ldsStage + 12288);       \
} while (0)

#define PHASE_A(ASC, Q, TAIL) do {                                             \
    const unsigned short* ap_ = (ASC) + aRowRd + ((Q) << 11);                  \
    short8 af0k0 = *(const short8*)(ap_ + pch0);                               \
    short8 af0k1 = *(const short8*)(ap_ + pch1);                               \
    short8 af1k0 = *(const short8*)(ap_ + 1024 + pch0);                        \
    short8 af1k1 = *(const short8*)(ap_ + 1024 + pch1);                        \
    BARRIER_F();                                                               \
    __builtin_amdgcn_s_setprio(1);                                             \
    _Pragma("unroll")                                                          \
    for (int ng = 0; ng < 4; ++ng) {                                           \
        acc[(Q)*2][ng]   = __builtin_amdgcn_mfma_f32_16x16x32_bf16(af0k0, bfr[ng][0], acc[(Q)*2][ng], 0, 0, 0);   \
        acc[(Q)*2][ng]   = __builtin_amdgcn_mfma_f32_16x16x32_bf16(af0k1, bfr[ng][1], acc[(Q)*2][ng], 0, 0, 0);   \
        acc[(Q)*2+1][ng] = __builtin_amdgcn_mfma_f32_16x16x32_bf16(af1k0, bfr[ng][0], acc[(Q)*2+1][ng], 0, 0, 0); \
        acc[(Q)*2+1][ng] = __builtin_amdgcn_mfma_f32_16x16x32_bf16(af1k1, bfr[ng][1], acc[(Q)*2+1][ng], 0, 0, 0); \
    }                                                                          \
    __builtin_amdgcn_s_setprio(0);                                             \
    TAIL;                                                                      \
    BARRIER_F();                                                               \
} while (0)

#define TILE(ASC, BSC, ASN, BSN, KTN, DOSTAGE) do {                            \
    short8 bfr[4][2];                                                          \
    if (DOSTAGE) { STAGE_TILE(ASN, BSN, KTN); }                                \
    _Pragma("unroll")                                                          \
    for (int ng = 0; ng < 4; ++ng) {                                           \
        bfr[ng][0] = *(const short8*)((BSC) + bRowRd + (ng << 10) + pch0);     \
        bfr[ng][1] = *(const short8*)((BSC) + bRowRd + (ng << 10) + pch1);     \
    }                                                                          \
    PHASE_A(ASC, 0, ((void)0));                                                \
    PHASE_A(ASC, 1, ((void)0));                                                \
    PHASE_A(ASC, 2, ((void)0));                                                \
    PHASE_A(ASC, 3, if (DOSTAGE) { VMCNT0; });                                 \
} while (0)

__global__ __launch_bounds__(512, 2) void gemm_gates_kernel(const unsigned short* __restrict__ xpad,
                                                            const unsigned short* __restrict__ Btw,
                                                            const float* __restrict__ bias,
                                                            unsigned short* __restrict__ zT) {
    extern __shared__ unsigned short lds[];          // 131072 B
    unsigned short* As0 = lds;                       // [256][64] bf16, swizzled chunks
    unsigned short* As1 = lds + 16384;
    unsigned short* Bs0 = lds + 32768;
    unsigned short* Bs1 = lds + 49152;

    const int tid  = threadIdx.x;
    const int lane = tid & 63;
    const int w    = tid >> 6;
    const int wm   = w >> 2;                         // 0..1 (M)
    const int wn   = w & 3;                          // 0..3 (N)
    const int mrow = lane & 15;
    const int quad = lane >> 4;

    const int m0 = blockIdx.x << 8;
    const int n0 = blockIdx.y << 8;
    const int bidx = m0 >> 10;                       // 256 | 1024: tile never straddles batch
    const int t0   = m0 & 1023;

    // staging precomputes: per gload call thread covers (row = r0 + tid>>3, chunk = tid&7)
    const int rr  = tid >> 3;
    const int cc8 = (((tid & 7) ^ (rr & 7)) << 3);   // pre-swizzled source chunk
    const size_t aSrc = (((size_t)(bidx * TP + t0 + rr)) << 10) + cc8;
    const size_t bSrc = (((size_t)(n0 + rr)) << 11) + cc8;
    const int ldsStage = (rr << 6) + ((tid & 7) << 3);   // linear LDS dest (lane*16B per wave)

    // fragment-read precomputes (row&7 == lane&7 for all frag rows)
    const int pch0 = ((quad ^ (lane & 7)) << 3);         // k-slice 0, swizzled chunk
    const int pch1 = (((4 | quad) ^ (lane & 7)) << 3);   // k-slice 1
    const int aRowRd = ((wm << 7) + mrow) << 6;
    const int bRowRd = ((wn << 6) + mrow) << 6;

    float4v acc[8][4];
#pragma unroll
    for (int i = 0; i < 8; ++i)
#pragma unroll
        for (int j = 0; j < 4; ++j) acc[i][j] = (float4v)0.0f;

    // prologue: stage K-tile 0, drain once, go
    STAGE_TILE(As0, Bs0, 0);
    VMCNT0;
    BARRIER_F();

#pragma unroll 1
    for (int jt = 0; jt < 30; jt += 2) {
        TILE(As0, Bs0, As1, Bs1, jt + 1, 1);
        TILE(As1, Bs1, As0, Bs0, jt + 2, 1);
    }
    TILE(As0, Bs0, As1, Bs1, 31, 1);                 // tile 30, stage 31
    TILE(As1, Bs1, As0, Bs0, 0, 0);                  // tile 31, no stage

    // ---------------- epilogue: bias + activation + LDS transpose + coalesced store --------
    unsigned short* Ts = lds;                        // [256 n][256 t] bf16, chunk-XOR swizzled
    const bool isZ = (n0 < HH);
    float bv[4];
#pragma unroll
    for (int ng = 0; ng < 4; ++ng) bv[ng] = bias[n0 + (wn << 6) + (ng << 4) + mrow];

#pragma unroll
    for (int g = 0; g < 8; ++g) {
#pragma unroll
        for (int ng = 0; ng < 4; ++ng) {
            const int nloc = (wn << 6) + (ng << 4) + mrow;          // tile row (n-local)
            const int m0l  = (wm << 7) + (g << 4) + (quad << 2);    // tile col (t-local), 4 consec
            float v0 = acc[g][ng][0] + bv[ng];
            float v1 = acc[g][ng][1] + bv[ng];
            float v2 = acc[g][ng][2] + bv[ng];
            float v3 = acc[g][ng][3] + bv[ng];
            float g0, g1, g2, g3;
            if (isZ) {
                g0 = 2.0f * __builtin_amdgcn_rcpf(1.0f + __expf(-2.0f * v0)) - 1.0f;
                g1 = 2.0f * __builtin_amdgcn_rcpf(1.0f + __expf(-2.0f * v1)) - 1.0f;
                g2 = 2.0f * __builtin_amdgcn_rcpf(1.0f + __expf(-2.0f * v2)) - 1.0f;
                g3 = 2.0f * __builtin_amdgcn_rcpf(1.0f + __expf(-2.0f * v3)) - 1.0f;
            } else {
                g0 = __builtin_amdgcn_rcpf(1.0f + __expf(-v0));
                g1 = __builtin_amdgcn_rcpf(1.0f + __expf(-v1));
                g2 = __builtin_amdgcn_rcpf(1.0f + __expf(-v2));
                g3 = __builtin_amdgcn_rcpf(1.0f + __expf(-v3));
            }
            unsigned int d0 = (unsigned int)f2bf(g0) | ((unsigned int)f2bf(g1) << 16);
            unsigned int d1 = (unsigned int)f2bf(g2) | ((unsigned int)f2bf(g3) << 16);
            const int chunk = (m0l >> 3) ^ (nloc & 31);             // 16B-chunk XOR swizzle
            *(uint2*)(Ts + nloc * 256 + (chunk << 3) + (m0l & 7)) = make_uint2(d0, d1);
        }
    }
    __syncthreads();

    // coalesced store: row np = n-local; 32 lanes x 16B cover 256 t
    const int gate = n0 >> 10;
    unsigned short* plane = zT + ((size_t)gate << 24);
    const int cl = lane & 31;
#pragma unroll
    for (int p = 0; p < 16; ++p) {
        const int np = (p << 4) + (tid >> 5);
        short8 vv = *(const short8*)(Ts + np * 256 + ((cl ^ (np & 31)) << 3));
        const int h = (n0 & 1023) + np;
        const size_t dst = ((((size_t)((bidx << 10) | h)) << 10) | (unsigned)(t0 + (cl << 3)));
        *(short8*)(plane + dst) = vv;
    }
}

// ---------------- chunked fo-pooling scan, 3 passes ----------------------------------------
// thread g: h = g & 1023, b = (g>>10)&15, chunk j = g>>14.  summaries at o = (j<<14)|(b<<10)|h

// Pass A: per-chunk summaries P = prod f, S = local scan from 0 (t-contiguous 16B loads)
__global__ __launch_bounds__(256) void scan_summary_kernel(const unsigned short* __restrict__ zT,
                                                           float* __restrict__ P,
                                                           float* __restrict__ S) {
    int g = blockIdx.x * 256 + threadIdx.x;        // [0, 524288)
    int h = g & 1023;
    int b = (g >> 10) & 15;
    int j = g >> 14;
    const unsigned short* zp = zT + ((((size_t)((b << 10) | h)) << 10) + j * TC);
    const unsigned short* fp = zp + PLANE;
    short8 zv[4], fv[4];
#pragma unroll
    for (int q = 0; q < 4; ++q) {
        zv[q] = *(const short8*)(zp + q * 8);
        fv[q] = *(const short8*)(fp + q * 8);
    }
    float c = 0.f, pr = 1.f;
#pragma unroll
    for (int q = 0; q < 4; ++q)
#pragma unroll
        for (int k = 0; k < 8; ++k) {
            float z = bf2f((unsigned short)zv[q][k]);
            float f = bf2f((unsigned short)fv[q][k]);
            c = fmaf(f, c, (1.0f - f) * z);
            pr *= f;
        }
    int o = (j << 14) | (b << 10) | h;
    P[o] = pr;
    S[o] = c;
}

// Pass B: scan the 32 chunk summaries per chain; Cin[j] = cell state entering chunk j
__global__ __launch_bounds__(256) void scan_prefix_kernel(const float* __restrict__ P,
                                                          const float* __restrict__ S,
                                                          float* __restrict__ Cin) {
    int idx = blockIdx.x * 256 + threadIdx.x;      // [0, 16384) = (b,h)
    float c = 0.f;
#pragma unroll
    for (int j = 0; j < NCH; ++j) {
        int o = (j << 14) + idx;
        Cin[o] = c;
        c = fmaf(P[o], c, S[o]);
    }
}

// Pass C: redo local scan seeded with Cin, write c and h = o*c (coalesced fp32 stores)
__global__ __launch_bounds__(256) void scan_apply_kernel(const unsigned short* __restrict__ zT,
                                                         const float* __restrict__ Cin,
                                                         float* __restrict__ out) {
    int g = blockIdx.x * 256 + threadIdx.x;        // [0, 524288)
    int h = g & 1023;
    int b = (g >> 10) & 15;
    int j = g >> 14;
    const unsigned short* zp = zT + ((((size_t)((b << 10) | h)) << 10) + j * TC);
    const unsigned short* fp = zp + PLANE;
    const unsigned short* op = zp + 2 * (size_t)PLANE;
    short8 zv[4], fv[4], ov[4];
#pragma unroll
    for (int q = 0; q < 4; ++q) {
        zv[q] = *(const short8*)(zp + q * 8);
        fv[q] = *(const short8*)(fp + q * 8);
        ov[q] = *(const short8*)(op + q * 8);
    }
    float c = Cin[(j << 14) | (b << 10) | h];
    float* cbase = out + ((((size_t)((b << 10) | (j * TC))) << 10) | h);
#pragma unroll
    for (int q = 0; q < 4; ++q)
#pragma unroll
        for (int k = 0; k < 8; ++k) {
            float z = bf2f((unsigned short)zv[q][k]);
            float f = bf2f((unsigned short)fv[q][k]);
            float o = bf2f((unsigned short)ov[q][k]);
            c = fmaf(f, c, (1.0f - f) * z);
            float* cp = cbase + (((size_t)(q * 8 + k)) << 10);
            cp[0] = c;
            cp[(size_t)1 << 24] = o * c;           // h-plane offset = BB*TT*HH
        }
}

extern "C" void kernel_launch(void* const* d_in, const int* in_sizes, int n_in,
                              void* d_out, int out_size, void* d_ws, size_t ws_size,
                              hipStream_t stream) {
    const float* x    = (const float*)d_in[0];   // [B,T,D] fp32
    const float* w    = (const float*)d_in[1];   // [3H,D,2] fp32
    const float* bias = (const float*)d_in[2];   // [3H] fp32
    float* out = (float*)d_out;                  // [2, B, T, H] fp32 (c then h)

    char* ws = (char*)d_ws;
    const size_t xpad_bytes = (size_t)BB * TP * DD * 2;        // 33,587,200
    const size_t btw_bytes  = (size_t)NN * KK * 2;             // 12,582,912
    unsigned short* xpad = (unsigned short*)ws;
    unsigned short* Btw  = (unsigned short*)(ws + xpad_bytes);
    unsigned short* zT   = (unsigned short*)(ws + xpad_bytes + btw_bytes);   // [3][B][H][T]
    // scan scratch aliases the xpad region (dead after the GEMM): 3 x 2 MB
    float* P   = (float*)ws;
    float* S   = (float*)(ws + (size_t)MM * NCH * 4);
    float* Cin = (float*)(ws + (size_t)MM * NCH * 8);

    {
        int total = BB * TP * (DD / 4);
        pack_x_kernel<<<(total + 255) / 256, 256, 0, stream>>>(x, xpad);
    }
    {
        int total = NN * DD;
        pack_w_kernel<<<(total + 255) / 256, 256, 0, stream>>>(w, Btw);
    }
    {
        static int gemm_attr_done = 0;
        if (!gemm_attr_done) {
            (void)hipFuncSetAttribute((const void*)gemm_gates_kernel,
                                      hipFuncAttributeMaxDynamicSharedMemorySize, 131072);
            gemm_attr_done = 1;
        }
        dim3 grid(MM / 256, NN / 256);   // 64 x 12 = 768 blocks (3 full CU rounds)
        gemm_gates_kernel<<<grid, 512, 131072, stream>>>(xpad, Btw, bias, zT);
    }
    scan_summary_kernel<<<MM * NCH / 256, 256, 0, stream>>>(zT, P, S);
    scan_prefix_kernel<<<MM / 256, 256, 0, stream>>>(P, S, Cin);
    scan_apply_kernel<<<MM * NCH / 256, 256, 0, stream>>>(zT, Cin, out);
}

// Round 2
// 449.599 us; speedup vs baseline: 1.1057x; 1.0215x over previous
//
#include <hip/hip_runtime.h>

// Problem constants
#define BB 16
#define TT 1024
#define DD 1024
#define HH 1024
#define NN 3072            // 3H
#define KK 2048            // 2D (two conv taps)
#define MM (BB * TT)       // 16384
#define TP (TT + 1)        // padded time rows in xpad (row 0 = zeros)
#define NCH 32             // scan chunks
#define TC  32             // steps per chunk (NCH*TC == TT)
#define PLANE (1u << 24)   // 16M elements per gate plane ( = BB*HH*TT )

typedef __attribute__((ext_vector_type(8))) short short8;   // 8 x bf16
typedef __attribute__((ext_vector_type(4))) float float4v;  // MFMA acc

__device__ __forceinline__ unsigned short f2bf(float f) {
    unsigned int u = __float_as_uint(f);
    u += 0x7fffu + ((u >> 16) & 1u);   // round-to-nearest-even
    return (unsigned short)(u >> 16);
}
__device__ __forceinline__ float bf2f(unsigned short s) {
    return __uint_as_float(((unsigned int)s) << 16);
}

// async global->LDS, 16B per lane; LDS dest semantics: wave-uniform base + lane*16
__device__ __forceinline__ void gload_lds16(const unsigned short* g, unsigned short* l) {
    __builtin_amdgcn_global_load_lds(
        (const __attribute__((address_space(1))) unsigned int*)(g),
        (__attribute__((address_space(3))) unsigned int*)(l),
        16, 0, 0);
}

// ---------------- pack x: fp32 [B,T,D] -> bf16 xpad [B, T+1, D], row 0 zero ----------------
__global__ __launch_bounds__(256) void pack_x_kernel(const float* __restrict__ x,
                                                     unsigned short* __restrict__ xpad) {
    int i = blockIdx.x * 256 + threadIdx.x;          // one float4 group
    int total = BB * TP * (DD / 4);
    if (i >= total) return;
    int d4  = i & (DD / 4 - 1);
    int row = i >> 8;                                // [0, B*TP)
    int b  = row / TP;
    int tp = row - b * TP;
    float4 v = make_float4(0.f, 0.f, 0.f, 0.f);
    if (tp > 0)
        v = ((const float4*)x)[(((size_t)(b * TT + tp - 1)) << 8) + d4];
    ushort4 r4;
    r4.x = f2bf(v.x); r4.y = f2bf(v.y); r4.z = f2bf(v.z); r4.w = f2bf(v.w);
    *(ushort4*)(xpad + (((size_t)row) << 10) + (d4 << 2)) = r4;
}

// ---------------- pack w: fp32 [3H, D, 2] -> bf16 Bt [N=3072][K=2048] (B^T layout) ----------
__global__ __launch_bounds__(256) void pack_w_kernel(const float* __restrict__ w,
                                                     unsigned short* __restrict__ Bt) {
    int i = blockIdx.x * 256 + threadIdx.x;          // n*1024 + d
    if (i >= NN * DD) return;
    int n = i >> 10, d = i & 1023;
    float2 v = ((const float2*)w)[i];                // (w[n,d,0], w[n,d,1])
    Bt[(size_t)n * KK + d]       = f2bf(v.x);        // tap0 at k = d
    Bt[(size_t)n * KK + DD + d]  = f2bf(v.y);        // tap1 at k = 1024 + d
}

// ---------------- GEMM: gates = A * W^T, fused bias + activation ---------------------------
// 256x256 tile, BK=64, 512 threads (8 waves as 2M x 4N, 128x64 per wave).
// ONE barrier per K-tile (not 8): within a tile all ds_reads hit one buffer; staging targets
// the other buffer and is issued right after the barrier -> full-tile prefetch lead, so the
// __syncthreads() vmcnt(0) drain is ~free. No intra-tile barriers: the compiler's
// fine-grained lgkmcnt waits + 2-waves/SIMD natural stagger overlap LDS service with MFMA.
// LDS chunk-swizzle: physical 16B chunk pc at row r holds logical chunk pc^(r&7); applied on
// the global SOURCE address (gload_lds writes linearly) and mirrored on ds_read addresses.

#define STAGE_TILE(ASN, BSN, KT) do {                                          \
    const int tap_ = (KT) >> 4;                                                \
    const size_t aoff_ = aSrc + (((size_t)tap_) << 10) + (((KT) & 15) << 6);   \
    const size_t boff_ = bSrc + (((size_t)(KT)) << 6);                         \
    gload_lds16(xpad + aoff_,                 (ASN) + ldsStage);               \
    gload_lds16(xpad + aoff_ + (64u << 10),   (ASN) + ldsStage + 4096);        \
    gload_lds16(xpad + aoff_ + (128u << 10),  (ASN) + ldsStage + 8192);        \
    gload_lds16(xpad + aoff_ + (192u << 10),  (ASN) + ldsStage + 12288);       \
    gload_lds16(Btw + boff_,                  (BSN) + ldsStage);               \
    gload_lds16(Btw + boff_ + (64u << 11),    (BSN) + ldsStage + 4096);        \
    gload_lds16(Btw + boff_ + (128u << 11),   (BSN) + ldsStage + 8192);        \
    gload_lds16(Btw + boff_ + (192u << 11),   (BSN) + ldsStage + 12288);       \
} while (0)

// one phase = one 32-row M-quadrant of the wave's 128x64 C, full K=64: 16 MFMA.
// k0 MFMAs first (8 independent accs), then k1 — no back-to-back same-acc dependency.
#define MFMA16(P, AA, AB, AC, AD) do {                                         \
    __builtin_amdgcn_s_setprio(1);                                             \
    acc[2*(P)  ][0] = __builtin_amdgcn_mfma_f32_16x16x32_bf16(AA, b00, acc[2*(P)  ][0], 0, 0, 0); \
    acc[2*(P)+1][0] = __builtin_amdgcn_mfma_f32_16x16x32_bf16(AB, b00, acc[2*(P)+1][0], 0, 0, 0); \
    acc[2*(P)  ][1] = __builtin_amdgcn_mfma_f32_16x16x32_bf16(AA, b10, acc[2*(P)  ][1], 0, 0, 0); \
    acc[2*(P)+1][1] = __builtin_amdgcn_mfma_f32_16x16x32_bf16(AB, b10, acc[2*(P)+1][1], 0, 0, 0); \
    acc[2*(P)  ][2] = __builtin_amdgcn_mfma_f32_16x16x32_bf16(AA, b20, acc[2*(P)  ][2], 0, 0, 0); \
    acc[2*(P)+1][2] = __builtin_amdgcn_mfma_f32_16x16x32_bf16(AB, b20, acc[2*(P)+1][2], 0, 0, 0); \
    acc[2*(P)  ][3] = __builtin_amdgcn_mfma_f32_16x16x32_bf16(AA, b30, acc[2*(P)  ][3], 0, 0, 0); \
    acc[2*(P)+1][3] = __builtin_amdgcn_mfma_f32_16x16x32_bf16(AB, b30, acc[2*(P)+1][3], 0, 0, 0); \
    acc[2*(P)  ][0] = __builtin_amdgcn_mfma_f32_16x16x32_bf16(AC, b01, acc[2*(P)  ][0], 0, 0, 0); \
    acc[2*(P)+1][0] = __builtin_amdgcn_mfma_f32_16x16x32_bf16(AD, b01, acc[2*(P)+1][0], 0, 0, 0); \
    acc[2*(P)  ][1] = __builtin_amdgcn_mfma_f32_16x16x32_bf16(AC, b11, acc[2*(P)  ][1], 0, 0, 0); \
    acc[2*(P)+1][1] = __builtin_amdgcn_mfma_f32_16x16x32_bf16(AD, b11, acc[2*(P)+1][1], 0, 0, 0); \
    acc[2*(P)  ][2] = __builtin_amdgcn_mfma_f32_16x16x32_bf16(AC, b21, acc[2*(P)  ][2], 0, 0, 0); \
    acc[2*(P)+1][2] = __builtin_amdgcn_mfma_f32_16x16x32_bf16(AD, b21, acc[2*(P)+1][2], 0, 0, 0); \
    acc[2*(P)  ][3] = __builtin_amdgcn_mfma_f32_16x16x32_bf16(AC, b31, acc[2*(P)  ][3], 0, 0, 0); \
    acc[2*(P)+1][3] = __builtin_amdgcn_mfma_f32_16x16x32_bf16(AD, b31, acc[2*(P)+1][3], 0, 0, 0); \
    __builtin_amdgcn_s_setprio(0);                                             \
} while (0)

#define TILE(ASC, BSC, ASN, BSN, KTN, DOSTAGE) do {                            \
    const unsigned short* aP_ = (ASC) + aRowRd;                                \
    const unsigned short* bP_ = (BSC) + bRowRd;                                \
    short8 b00 = *(const short8*)(bP_ +    0 + pch0);                          \
    short8 b10 = *(const short8*)(bP_ + 1024 + pch0);                          \
    short8 b20 = *(const short8*)(bP_ + 2048 + pch0);                          \
    short8 b30 = *(const short8*)(bP_ + 3072 + pch0);                          \
    short8 aAx = *(const short8*)(aP_ +    0 + pch0);                          \
    short8 aBx = *(const short8*)(aP_ + 1024 + pch0);                          \
    short8 b01 = *(const short8*)(bP_ +    0 + pch1);                          \
    short8 b11 = *(const short8*)(bP_ + 1024 + pch1);                          \
    short8 b21 = *(const short8*)(bP_ + 2048 + pch1);                          \
    short8 b31 = *(const short8*)(bP_ + 3072 + pch1);                          \
    short8 aCx = *(const short8*)(aP_ +    0 + pch1);                          \
    short8 aDx = *(const short8*)(aP_ + 1024 + pch1);                          \
    if (DOSTAGE) { STAGE_TILE(ASN, BSN, KTN); }                                \
    MFMA16(0, aAx, aBx, aCx, aDx);                                             \
    aAx = *(const short8*)(aP_ + 2048 + pch0);                                 \
    aBx = *(const short8*)(aP_ + 3072 + pch0);                                 \
    aCx = *(const short8*)(aP_ + 2048 + pch1);                                 \
    aDx = *(const short8*)(aP_ + 3072 + pch1);                                 \
    MFMA16(1, aAx, aBx, aCx, aDx);                                             \
    aAx = *(const short8*)(aP_ + 4096 + pch0);                                 \
    aBx = *(const short8*)(aP_ + 5120 + pch0);                                 \
    aCx = *(const short8*)(aP_ + 4096 + pch1);                                 \
    aDx = *(const short8*)(aP_ + 5120 + pch1);                                 \
    MFMA16(2, aAx, aBx, aCx, aDx);                                             \
    aAx = *(const short8*)(aP_ + 6144 + pch0);                                 \
    aBx = *(const short8*)(aP_ + 7168 + pch0);                                 \
    aCx = *(const short8*)(aP_ + 6144 + pch1);                                 \
    aDx = *(const short8*)(aP_ + 7168 + pch1);                                 \
    MFMA16(3, aAx, aBx, aCx, aDx);                                             \
    __syncthreads();                                                           \
} while (0)

__global__ __launch_bounds__(512, 2) void gemm_gates_kernel(const unsigned short* __restrict__ xpad,
                                                            const unsigned short* __restrict__ Btw,
                                                            const float* __restrict__ bias,
                                                            unsigned short* __restrict__ zT) {
    extern __shared__ unsigned short lds[];          // 131072 B
    unsigned short* As0 = lds;                       // [256][64] bf16, swizzled chunks
    unsigned short* As1 = lds + 16384;
    unsigned short* Bs0 = lds + 32768;
    unsigned short* Bs1 = lds + 49152;

    const int tid  = threadIdx.x;
    const int lane = tid & 63;
    const int w    = tid >> 6;
    const int wm   = w >> 2;                         // 0..1 (M)
    const int wn   = w & 3;                          // 0..3 (N)
    const int mrow = lane & 15;
    const int quad = lane >> 4;

    const int m0 = blockIdx.x << 8;
    const int n0 = blockIdx.y << 8;
    const int bidx = m0 >> 10;                       // 256 | 1024: tile never straddles batch
    const int t0   = m0 & 1023;

    // staging precomputes: per gload call thread covers (row = r0 + tid>>3, chunk = tid&7)
    const int rr  = tid >> 3;
    const int cc8 = (((tid & 7) ^ (rr & 7)) << 3);   // pre-swizzled source chunk
    const size_t aSrc = (((size_t)(bidx * TP + t0 + rr)) << 10) + cc8;
    const size_t bSrc = (((size_t)(n0 + rr)) << 11) + cc8;
    const int ldsStage = (rr << 6) + ((tid & 7) << 3);   // linear LDS dest (lane*16B per wave)

    // fragment-read precomputes (row&7 == lane&7 for all frag rows)
    const int pch0 = ((quad ^ (lane & 7)) << 3);         // k-slice 0, swizzled chunk
    const int pch1 = (((4 | quad) ^ (lane & 7)) << 3);   // k-slice 1
    const int aRowRd = ((wm << 7) + mrow) << 6;
    const int bRowRd = ((wn << 6) + mrow) << 6;

    float4v acc[8][4];
#pragma unroll
    for (int i = 0; i < 8; ++i)
#pragma unroll
        for (int j = 0; j < 4; ++j) acc[i][j] = (float4v)0.0f;

    // prologue: stage K-tile 0, drain once (inside __syncthreads), go
    STAGE_TILE(As0, Bs0, 0);
    __syncthreads();

#pragma unroll 1
    for (int jt = 0; jt < 30; jt += 2) {
        TILE(As0, Bs0, As1, Bs1, jt + 1, 1);
        TILE(As1, Bs1, As0, Bs0, jt + 2, 1);
    }
    TILE(As0, Bs0, As1, Bs1, 31, 1);                 // tile 30, stage 31
    TILE(As1, Bs1, As0, Bs0, 0, 0);                  // tile 31, no stage

    // ---------------- epilogue: bias + activation + LDS transpose + coalesced store --------
    unsigned short* Ts = lds;                        // [256 n][256 t] bf16, chunk-XOR swizzled
    const bool isZ = (n0 < HH);
    float bv[4];
#pragma unroll
    for (int ng = 0; ng < 4; ++ng) bv[ng] = bias[n0 + (wn << 6) + (ng << 4) + mrow];

#pragma unroll
    for (int g = 0; g < 8; ++g) {
#pragma unroll
        for (int ng = 0; ng < 4; ++ng) {
            const int nloc = (wn << 6) + (ng << 4) + mrow;          // tile row (n-local)
            const int m0l  = (wm << 7) + (g << 4) + (quad << 2);    // tile col (t-local), 4 consec
            float v0 = acc[g][ng][0] + bv[ng];
            float v1 = acc[g][ng][1] + bv[ng];
            float v2 = acc[g][ng][2] + bv[ng];
            float v3 = acc[g][ng][3] + bv[ng];
            float g0, g1, g2, g3;
            if (isZ) {
                g0 = 2.0f * __builtin_amdgcn_rcpf(1.0f + __expf(-2.0f * v0)) - 1.0f;
                g1 = 2.0f * __builtin_amdgcn_rcpf(1.0f + __expf(-2.0f * v1)) - 1.0f;
                g2 = 2.0f * __builtin_amdgcn_rcpf(1.0f + __expf(-2.0f * v2)) - 1.0f;
                g3 = 2.0f * __builtin_amdgcn_rcpf(1.0f + __expf(-2.0f * v3)) - 1.0f;
            } else {
                g0 = __builtin_amdgcn_rcpf(1.0f + __expf(-v0));
                g1 = __builtin_amdgcn_rcpf(1.0f + __expf(-v1));
                g2 = __builtin_amdgcn_rcpf(1.0f + __expf(-v2));
                g3 = __builtin_amdgcn_rcpf(1.0f + __expf(-v3));
            }
            unsigned int d0 = (unsigned int)f2bf(g0) | ((unsigned int)f2bf(g1) << 16);
            unsigned int d1 = (unsigned int)f2bf(g2) | ((unsigned int)f2bf(g3) << 16);
            const int chunk = (m0l >> 3) ^ (nloc & 31);             // 16B-chunk XOR swizzle
            *(uint2*)(Ts + nloc * 256 + (chunk << 3) + (m0l & 7)) = make_uint2(d0, d1);
        }
    }
    __syncthreads();

    // coalesced store: row np = n-local; 32 lanes x 16B cover 256 t
    const int gate = n0 >> 10;
    unsigned short* plane = zT + ((size_t)gate << 24);
    const int cl = lane & 31;
#pragma unroll
    for (int p = 0; p < 16; ++p) {
        const int np = (p << 4) + (tid >> 5);
        short8 vv = *(const short8*)(Ts + np * 256 + ((cl ^ (np & 31)) << 3));
        const int h = (n0 & 1023) + np;
        const size_t dst = ((((size_t)((bidx << 10) | h)) << 10) | (unsigned)(t0 + (cl << 3)));
        *(short8*)(plane + dst) = vv;
    }
}

// ---------------- chunked fo-pooling scan, 3 passes ----------------------------------------
// thread g: h = g & 1023, b = (g>>10)&15, chunk j = g>>14.  summaries at o = (j<<14)|(b<<10)|h

// Pass A: per-chunk summaries P = prod f, S = local scan from 0 (t-contiguous 16B loads)
__global__ __launch_bounds__(256) void scan_summary_kernel(const unsigned short* __restrict__ zT,
                                                           float* __restrict__ P,
                                                           float* __restrict__ S) {
    int g = blockIdx.x * 256 + threadIdx.x;        // [0, 524288)
    int h = g & 1023;
    int b = (g >> 10) & 15;
    int j = g >> 14;
    const unsigned short* zp = zT + ((((size_t)((b << 10) | h)) << 10) + j * TC);
    const unsigned short* fp = zp + PLANE;
    short8 zv[4], fv[4];
#pragma unroll
    for (int q = 0; q < 4; ++q) {
        zv[q] = *(const short8*)(zp + q * 8);
        fv[q] = *(const short8*)(fp + q * 8);
    }
    float c = 0.f, pr = 1.f;
#pragma unroll
    for (int q = 0; q < 4; ++q)
#pragma unroll
        for (int k = 0; k < 8; ++k) {
            float z = bf2f((unsigned short)zv[q][k]);
            float f = bf2f((unsigned short)fv[q][k]);
            c = fmaf(f, c, (1.0f - f) * z);
            pr *= f;
        }
    int o = (j << 14) | (b << 10) | h;
    P[o] = pr;
    S[o] = c;
}

// Pass B: scan the 32 chunk summaries per chain; Cin[j] = cell state entering chunk j
__global__ __launch_bounds__(256) void scan_prefix_kernel(const float* __restrict__ P,
                                                          const float* __restrict__ S,
                                                          float* __restrict__ Cin) {
    int idx = blockIdx.x * 256 + threadIdx.x;      // [0, 16384) = (b,h)
    float c = 0.f;
#pragma unroll
    for (int j = 0; j < NCH; ++j) {
        int o = (j << 14) + idx;
        Cin[o] = c;
        c = fmaf(P[o], c, S[o]);
    }
}

// Pass C: redo local scan seeded with Cin, write c and h = o*c (coalesced fp32 stores)
__global__ __launch_bounds__(256) void scan_apply_kernel(const unsigned short* __restrict__ zT,
                                                         const float* __restrict__ Cin,
                                                         float* __restrict__ out) {
    int g = blockIdx.x * 256 + threadIdx.x;        // [0, 524288)
    int h = g & 1023;
    int b = (g >> 10) & 15;
    int j = g >> 14;
    const unsigned short* zp = zT + ((((size_t)((b << 10) | h)) << 10) + j * TC);
    const unsigned short* fp = zp + PLANE;
    const unsigned short* op = zp + 2 * (size_t)PLANE;
    short8 zv[4], fv[4], ov[4];
#pragma unroll
    for (int q = 0; q < 4; ++q) {
        zv[q] = *(const short8*)(zp + q * 8);
        fv[q] = *(const short8*)(fp + q * 8);
        ov[q] = *(const short8*)(op + q * 8);
    }
    float c = Cin[(j << 14) | (b << 10) | h];
    float* cbase = out + ((((size_t)((b << 10) | (j * TC))) << 10) | h);
#pragma unroll
    for (int q = 0; q < 4; ++q)
#pragma unroll
        for (int k = 0; k < 8; ++k) {
            float z = bf2f((unsigned short)zv[q][k]);
            float f = bf2f((unsigned short)fv[q][k]);
            float o = bf2f((unsigned short)ov[q][k]);
            c = fmaf(f, c, (1.0f - f) * z);
            float* cp = cbase + (((size_t)(q * 8 + k)) << 10);
            cp[0] = c;
            cp[(size_t)1 << 24] = o * c;           // h-plane offset = BB*TT*HH
        }
}

extern "C" void kernel_launch(void* const* d_in, const int* in_sizes, int n_in,
                              void* d_out, int out_size, void* d_ws, size_t ws_size,
                              hipStream_t stream) {
    const float* x    = (const float*)d_in[0];   // [B,T,D] fp32
    const float* w    = (const float*)d_in[1];   // [3H,D,2] fp32
    const float* bias = (const float*)d_in[2];   // [3H] fp32
    float* out = (float*)d_out;                  // [2, B, T, H] fp32 (c then h)

    char* ws = (char*)d_ws;
    const size_t xpad_bytes = (size_t)BB * TP * DD * 2;        // 33,587,200
    const size_t btw_bytes  = (size_t)NN * KK * 2;             // 12,582,912
    unsigned short* xpad = (unsigned short*)ws;
    unsigned short* Btw  = (unsigned short*)(ws + xpad_bytes);
    unsigned short* zT   = (unsigned short*)(ws + xpad_bytes + btw_bytes);   // [3][B][H][T]
    // scan scratch aliases the xpad region (dead after the GEMM): 3 x 2 MB
    float* P   = (float*)ws;
    float* S   = (float*)(ws + (size_t)MM * NCH * 4);
    float* Cin = (float*)(ws + (size_t)MM * NCH * 8);

    {
        int total = BB * TP * (DD / 4);
        pack_x_kernel<<<(total + 255) / 256, 256, 0, stream>>>(x, xpad);
    }
    {
        int total = NN * DD;
        pack_w_kernel<<<(total + 255) / 256, 256, 0, stream>>>(w, Btw);
    }
    {
        static int gemm_attr_done = 0;
        if (!gemm_attr_done) {
            (void)hipFuncSetAttribute((const void*)gemm_gates_kernel,
                                      hipFuncAttributeMaxDynamicSharedMemorySize, 131072);
            gemm_attr_done = 1;
        }
        dim3 grid(MM / 256, NN / 256);   // 64 x 12 = 768 blocks (3 full CU rounds)
        gemm_gates_kernel<<<grid, 512, 131072, stream>>>(xpad, Btw, bias, zT);
    }
    scan_summary_kernel<<<MM * NCH / 256, 256, 0, stream>>>(zT, P, S);
    scan_prefix_kernel<<<MM / 256, 256, 0, stream>>>(P, S, Cin);
    scan_apply_kernel<<<MM * NCH / 256, 256, 0, stream>>>(zT, Cin, out);
}

// Round 3
// 443.588 us; speedup vs baseline: 1.1207x; 1.0136x over previous
//
#include <hip/hip_runtime.h>

// Problem constants
#define BB 16
#define TT 1024
#define DD 1024
#define HH 1024
#define NN 3072            // 3H
#define KK 2048            // 2D (two conv taps)
#define MM (BB * TT)       // 16384
#define TP (TT + 1)        // padded time rows in xpad (row 0 = zeros)
#define NCH 32             // scan chunks
#define TC  32             // steps per chunk (NCH*TC == TT)
#define PLANE (1u << 24)   // 16M elements per gate plane ( = BB*HH*TT )

typedef __attribute__((ext_vector_type(8))) short short8;   // 8 x bf16
typedef __attribute__((ext_vector_type(4))) float float4v;  // MFMA acc

__device__ __forceinline__ unsigned short f2bf(float f) {
    unsigned int u = __float_as_uint(f);
    u += 0x7fffu + ((u >> 16) & 1u);   // round-to-nearest-even
    return (unsigned short)(u >> 16);
}
__device__ __forceinline__ float bf2f(unsigned short s) {
    return __uint_as_float(((unsigned int)s) << 16);
}

// async global->LDS, 16B per lane; LDS dest semantics: wave-uniform base + lane*16
__device__ __forceinline__ void gload_lds16(const unsigned short* g, unsigned short* l) {
    __builtin_amdgcn_global_load_lds(
        (const __attribute__((address_space(1))) unsigned int*)(g),
        (__attribute__((address_space(3))) unsigned int*)(l),
        16, 0, 0);
}

// ---------------- pack x: fp32 [B,T,D] -> bf16 xpad [B, T+1, D], row 0 zero ----------------
__global__ __launch_bounds__(256) void pack_x_kernel(const float* __restrict__ x,
                                                     unsigned short* __restrict__ xpad) {
    int i = blockIdx.x * 256 + threadIdx.x;          // one float4 group
    int total = BB * TP * (DD / 4);
    if (i >= total) return;
    int d4  = i & (DD / 4 - 1);
    int row = i >> 8;                                // [0, B*TP)
    int b  = row / TP;
    int tp = row - b * TP;
    float4 v = make_float4(0.f, 0.f, 0.f, 0.f);
    if (tp > 0)
        v = ((const float4*)x)[(((size_t)(b * TT + tp - 1)) << 8) + d4];
    ushort4 r4;
    r4.x = f2bf(v.x); r4.y = f2bf(v.y); r4.z = f2bf(v.z); r4.w = f2bf(v.w);
    *(ushort4*)(xpad + (((size_t)row) << 10) + (d4 << 2)) = r4;
}

// ---------------- pack w: fp32 [3H, D, 2] -> bf16 Bt [N=3072][K=2048] (B^T layout) ----------
__global__ __launch_bounds__(256) void pack_w_kernel(const float* __restrict__ w,
                                                     unsigned short* __restrict__ Bt) {
    int i = blockIdx.x * 256 + threadIdx.x;          // n*1024 + d
    if (i >= NN * DD) return;
    int n = i >> 10, d = i & 1023;
    float2 v = ((const float2*)w)[i];                // (w[n,d,0], w[n,d,1])
    Bt[(size_t)n * KK + d]       = f2bf(v.x);        // tap0 at k = d
    Bt[(size_t)n * KK + DD + d]  = f2bf(v.y);        // tap1 at k = 1024 + d
}

// ---------------- GEMM: gates = A * W^T, fused bias + activation ---------------------------
// 256x256 tile, BK=64, 512 threads (8 waves as 2M x 4N, 128x64 per wave).
// m201-style 4-phase schedule, 2 barriers/phase, counted vmcnt (never 0 in main loop):
//   ph1: read 8 B-frags + A-quad0 | stage BOTH A-halves of tile t+1 (dead buffer) | bar | MFMA | bar
//   ph2: read A-quad1             | stage B-half0 of tile t+2 (into READ buffer: B-frags
//                                   are dead after ph1, issue is 2 barriers later)  | bar | MFMA | bar
//   ph3: read A-quad2             | stage B-half1 of tile t+2                       | bar | MFMA | bar
//   ph4: read A-quad3 | vmcnt(4) (allows only t+2's 4 B-calls outstanding -> tile t+1
//                       certified resident at the barrier) | bar | MFMA | bar
// LDS chunk-swizzle: physical 16B chunk pc at row r holds logical chunk pc^(r&7); applied on
// the global SOURCE address (gload_lds writes linearly) and mirrored on ds_read addresses.

#define CFENCE asm volatile("" ::: "memory")

#define STAGE_A_HALF(ASN, KT, HALF) do {                                       \
    const int tapA_ = (KT) >> 4;                                               \
    const size_t aoffA_ = aSrc + (((size_t)tapA_) << 10) + (((KT) & 15) << 6)  \
                        + (((size_t)(HALF)) << 17);                            \
    gload_lds16(xpad + aoffA_,               (ASN) + (HALF) * 8192 + ldsStage);        \
    gload_lds16(xpad + aoffA_ + (64u << 10), (ASN) + (HALF) * 8192 + ldsStage + 4096); \
} while (0)

#define STAGE_B_HALF(BSN, KT, HALF) do {                                       \
    const size_t boffB_ = bSrc + (((size_t)(KT)) << 6) + (((size_t)(HALF)) << 18); \
    gload_lds16(Btw + boffB_,               (BSN) + (HALF) * 8192 + ldsStage);        \
    gload_lds16(Btw + boffB_ + (64u << 11), (BSN) + (HALF) * 8192 + ldsStage + 4096); \
} while (0)

// one phase's MFMA cluster: one 32-row M-quadrant of the wave's 128x64 C, full K=64.
// k0 MFMAs first (8 independent accs), then k1 — no back-to-back same-acc dependency.
#define MFMA16(P, AA, AB, AC, AD) do {                                         \
    __builtin_amdgcn_s_setprio(1);                                             \
    acc[2*(P)  ][0] = __builtin_amdgcn_mfma_f32_16x16x32_bf16(AA, b00, acc[2*(P)  ][0], 0, 0, 0); \
    acc[2*(P)+1][0] = __builtin_amdgcn_mfma_f32_16x16x32_bf16(AB, b00, acc[2*(P)+1][0], 0, 0, 0); \
    acc[2*(P)  ][1] = __builtin_amdgcn_mfma_f32_16x16x32_bf16(AA, b10, acc[2*(P)  ][1], 0, 0, 0); \
    acc[2*(P)+1][1] = __builtin_amdgcn_mfma_f32_16x16x32_bf16(AB, b10, acc[2*(P)+1][1], 0, 0, 0); \
    acc[2*(P)  ][2] = __builtin_amdgcn_mfma_f32_16x16x32_bf16(AA, b20, acc[2*(P)  ][2], 0, 0, 0); \
    acc[2*(P)+1][2] = __builtin_amdgcn_mfma_f32_16x16x32_bf16(AB, b20, acc[2*(P)+1][2], 0, 0, 0); \
    acc[2*(P)  ][3] = __builtin_amdgcn_mfma_f32_16x16x32_bf16(AA, b30, acc[2*(P)  ][3], 0, 0, 0); \
    acc[2*(P)+1][3] = __builtin_amdgcn_mfma_f32_16x16x32_bf16(AB, b30, acc[2*(P)+1][3], 0, 0, 0); \
    acc[2*(P)  ][0] = __builtin_amdgcn_mfma_f32_16x16x32_bf16(AC, b01, acc[2*(P)  ][0], 0, 0, 0); \
    acc[2*(P)+1][0] = __builtin_amdgcn_mfma_f32_16x16x32_bf16(AD, b01, acc[2*(P)+1][0], 0, 0, 0); \
    acc[2*(P)  ][1] = __builtin_amdgcn_mfma_f32_16x16x32_bf16(AC, b11, acc[2*(P)  ][1], 0, 0, 0); \
    acc[2*(P)+1][1] = __builtin_amdgcn_mfma_f32_16x16x32_bf16(AD, b11, acc[2*(P)+1][1], 0, 0, 0); \
    acc[2*(P)  ][2] = __builtin_amdgcn_mfma_f32_16x16x32_bf16(AC, b21, acc[2*(P)  ][2], 0, 0, 0); \
    acc[2*(P)+1][2] = __builtin_amdgcn_mfma_f32_16x16x32_bf16(AD, b21, acc[2*(P)+1][2], 0, 0, 0); \
    acc[2*(P)  ][3] = __builtin_amdgcn_mfma_f32_16x16x32_bf16(AC, b31, acc[2*(P)  ][3], 0, 0, 0); \
    acc[2*(P)+1][3] = __builtin_amdgcn_mfma_f32_16x16x32_bf16(AD, b31, acc[2*(P)+1][3], 0, 0, 0); \
    __builtin_amdgcn_s_setprio(0);                                             \
} while (0)

#define TILE8(AC_, BC_, AN_, T) do {                                           \
    const int kA_ = ((T) + 1 < 32) ? ((T) + 1) : 31;                           \
    const int kB_ = ((T) + 2 < 32) ? ((T) + 2) : 31;                           \
    const unsigned short* aP_ = (AC_) + aRowRd;                                \
    const unsigned short* bP_ = (BC_) + bRowRd;                                \
    /* ---- phase 1 ---- */                                                    \
    short8 b00 = *(const short8*)(bP_ +    0 + pch0);                          \
    short8 b10 = *(const short8*)(bP_ + 1024 + pch0);                          \
    short8 b20 = *(const short8*)(bP_ + 2048 + pch0);                          \
    short8 b30 = *(const short8*)(bP_ + 3072 + pch0);                          \
    short8 b01 = *(const short8*)(bP_ +    0 + pch1);                          \
    short8 b11 = *(const short8*)(bP_ + 1024 + pch1);                          \
    short8 b21 = *(const short8*)(bP_ + 2048 + pch1);                          \
    short8 b31 = *(const short8*)(bP_ + 3072 + pch1);                          \
    short8 aAx = *(const short8*)(aP_ +    0 + pch0);                          \
    short8 aBx = *(const short8*)(aP_ + 1024 + pch0);                          \
    short8 aCx = *(const short8*)(aP_ +    0 + pch1);                          \
    short8 aDx = *(const short8*)(aP_ + 1024 + pch1);                          \
    STAGE_A_HALF(AN_, kA_, 0);                                                 \
    STAGE_A_HALF(AN_, kA_, 1);                                                 \
    asm volatile("s_waitcnt lgkmcnt(8)" ::: "memory");                         \
    CFENCE; __builtin_amdgcn_s_barrier(); CFENCE;                              \
    MFMA16(0, aAx, aBx, aCx, aDx);                                             \
    CFENCE; __builtin_amdgcn_s_barrier(); CFENCE;                              \
    /* ---- phase 2 ---- */                                                    \
    aAx = *(const short8*)(aP_ + 2048 + pch0);                                 \
    aBx = *(const short8*)(aP_ + 3072 + pch0);                                 \
    aCx = *(const short8*)(aP_ + 2048 + pch1);                                 \
    aDx = *(const short8*)(aP_ + 3072 + pch1);                                 \
    STAGE_B_HALF(BC_, kB_, 0);                                                 \
    CFENCE; __builtin_amdgcn_s_barrier(); CFENCE;                              \
    MFMA16(1, aAx, aBx, aCx, aDx);                                             \
    CFENCE; __builtin_amdgcn_s_barrier(); CFENCE;                              \
    /* ---- phase 3 ---- */                                                    \
    aAx = *(const short8*)(aP_ + 4096 + pch0);                                 \
    aBx = *(const short8*)(aP_ + 5120 + pch0);                                 \
    aCx = *(const short8*)(aP_ + 4096 + pch1);                                 \
    aDx = *(const short8*)(aP_ + 5120 + pch1);                                 \
    STAGE_B_HALF(BC_, kB_, 1);                                                 \
    CFENCE; __builtin_amdgcn_s_barrier(); CFENCE;                              \
    MFMA16(2, aAx, aBx, aCx, aDx);                                             \
    CFENCE; __builtin_amdgcn_s_barrier(); CFENCE;                              \
    /* ---- phase 4 ---- */                                                    \
    aAx = *(const short8*)(aP_ + 6144 + pch0);                                 \
    aBx = *(const short8*)(aP_ + 7168 + pch0);                                 \
    aCx = *(const short8*)(aP_ + 6144 + pch1);                                 \
    aDx = *(const short8*)(aP_ + 7168 + pch1);                                 \
    asm volatile("s_waitcnt vmcnt(4)" ::: "memory");                           \
    CFENCE; __builtin_amdgcn_s_barrier(); CFENCE;                              \
    MFMA16(3, aAx, aBx, aCx, aDx);                                             \
    CFENCE; __builtin_amdgcn_s_barrier(); CFENCE;                              \
} while (0)

__global__ __launch_bounds__(512, 2) void gemm_gates_kernel(const unsigned short* __restrict__ xpad,
                                                            const unsigned short* __restrict__ Btw,
                                                            const float* __restrict__ bias,
                                                            unsigned short* __restrict__ zT) {
    extern __shared__ unsigned short lds[];          // 131072 B
    unsigned short* As0 = lds;                       // [256][64] bf16, swizzled chunks
    unsigned short* As1 = lds + 16384;
    unsigned short* Bs0 = lds + 32768;
    unsigned short* Bs1 = lds + 49152;

    const int tid  = threadIdx.x;
    const int lane = tid & 63;
    const int w    = tid >> 6;
    const int wm   = w >> 2;                         // 0..1 (M)
    const int wn   = w & 3;                          // 0..3 (N)
    const int mrow = lane & 15;
    const int quad = lane >> 4;

    const int m0 = blockIdx.x << 8;
    const int n0 = blockIdx.y << 8;
    const int bidx = m0 >> 10;                       // 256 | 1024: tile never straddles batch
    const int t0   = m0 & 1023;

    // staging precomputes: per gload call thread covers (row = r0 + tid>>3, chunk = tid&7)
    const int rr  = tid >> 3;
    const int cc8 = (((tid & 7) ^ (rr & 7)) << 3);   // pre-swizzled source chunk
    const size_t aSrc = (((size_t)(bidx * TP + t0 + rr)) << 10) + cc8;
    const size_t bSrc = (((size_t)(n0 + rr)) << 11) + cc8;
    const int ldsStage = (rr << 6) + ((tid & 7) << 3);   // linear LDS dest (lane*16B per wave)

    // fragment-read precomputes (row&7 == lane&7 for all frag rows)
    const int pch0 = ((quad ^ (lane & 7)) << 3);         // k-slice 0, swizzled chunk
    const int pch1 = (((4 | quad) ^ (lane & 7)) << 3);   // k-slice 1
    const int aRowRd = ((wm << 7) + mrow) << 6;
    const int bRowRd = ((wn << 6) + mrow) << 6;

    float4v acc[8][4];
#pragma unroll
    for (int i = 0; i < 8; ++i)
#pragma unroll
        for (int j = 0; j < 4; ++j) acc[i][j] = (float4v)0.0f;

    // prologue: stage tile 0 fully + B-halves of tile 1; certify tile 0 (vmcnt(4)); go.
    STAGE_B_HALF(Bs0, 0, 0);
    STAGE_B_HALF(Bs0, 0, 1);
    STAGE_A_HALF(As0, 0, 0);
    STAGE_A_HALF(As0, 0, 1);
    STAGE_B_HALF(Bs1, 1, 0);
    STAGE_B_HALF(Bs1, 1, 1);
    asm volatile("s_waitcnt vmcnt(4)" ::: "memory");
    CFENCE; __builtin_amdgcn_s_barrier(); CFENCE;

#pragma unroll 1
    for (int t = 0; t < 32; t += 2) {
        TILE8(As0, Bs0, As1, t);         // reads buf0; A(t+1)->As1; B(t+2)->Bs0
        TILE8(As1, Bs1, As0, t + 1);     // reads buf1; A(t+2)->As0; B(t+3)->Bs1
    }
    __syncthreads();                      // drain tail garbage stages before LDS reuse

    // ---------------- epilogue: bias + activation + LDS transpose + coalesced store --------
    unsigned short* Ts = lds;                        // [256 n][256 t] bf16, chunk-XOR swizzled
    const bool isZ = (n0 < HH);
    float bv[4];
#pragma unroll
    for (int ng = 0; ng < 4; ++ng) bv[ng] = bias[n0 + (wn << 6) + (ng << 4) + mrow];

#pragma unroll
    for (int g = 0; g < 8; ++g) {
#pragma unroll
        for (int ng = 0; ng < 4; ++ng) {
            const int nloc = (wn << 6) + (ng << 4) + mrow;          // tile row (n-local)
            const int m0l  = (wm << 7) + (g << 4) + (quad << 2);    // tile col (t-local), 4 consec
            float v0 = acc[g][ng][0] + bv[ng];
            float v1 = acc[g][ng][1] + bv[ng];
            float v2 = acc[g][ng][2] + bv[ng];
            float v3 = acc[g][ng][3] + bv[ng];
            float g0, g1, g2, g3;
            if (isZ) {
                g0 = 2.0f * __builtin_amdgcn_rcpf(1.0f + __expf(-2.0f * v0)) - 1.0f;
                g1 = 2.0f * __builtin_amdgcn_rcpf(1.0f + __expf(-2.0f * v1)) - 1.0f;
                g2 = 2.0f * __builtin_amdgcn_rcpf(1.0f + __expf(-2.0f * v2)) - 1.0f;
                g3 = 2.0f * __builtin_amdgcn_rcpf(1.0f + __expf(-2.0f * v3)) - 1.0f;
            } else {
                g0 = __builtin_amdgcn_rcpf(1.0f + __expf(-v0));
                g1 = __builtin_amdgcn_rcpf(1.0f + __expf(-v1));
                g2 = __builtin_amdgcn_rcpf(1.0f + __expf(-v2));
                g3 = __builtin_amdgcn_rcpf(1.0f + __expf(-v3));
            }
            unsigned int d0 = (unsigned int)f2bf(g0) | ((unsigned int)f2bf(g1) << 16);
            unsigned int d1 = (unsigned int)f2bf(g2) | ((unsigned int)f2bf(g3) << 16);
            const int chunk = (m0l >> 3) ^ (nloc & 31);             // 16B-chunk XOR swizzle
            *(uint2*)(Ts + nloc * 256 + (chunk << 3) + (m0l & 7)) = make_uint2(d0, d1);
        }
    }
    __syncthreads();

    // coalesced store: row np = n-local; 32 lanes x 16B cover 256 t
    const int gate = n0 >> 10;
    unsigned short* plane = zT + ((size_t)gate << 24);
    const int cl = lane & 31;
#pragma unroll
    for (int p = 0; p < 16; ++p) {
        const int np = (p << 4) + (tid >> 5);
        short8 vv = *(const short8*)(Ts + np * 256 + ((cl ^ (np & 31)) << 3));
        const int h = (n0 & 1023) + np;
        const size_t dst = ((((size_t)((bidx << 10) | h)) << 10) | (unsigned)(t0 + (cl << 3)));
        *(short8*)(plane + dst) = vv;
    }
}

// ---------------- chunked fo-pooling scan, 3 passes ----------------------------------------
// thread g: h = g & 1023, b = (g>>10)&15, chunk j = g>>14.  summaries at o = (j<<14)|(b<<10)|h

// Pass A: per-chunk summaries P = prod f, S = local scan from 0 (t-contiguous 16B loads)
__global__ __launch_bounds__(256) void scan_summary_kernel(const unsigned short* __restrict__ zT,
                                                           float* __restrict__ P,
                                                           float* __restrict__ S) {
    int g = blockIdx.x * 256 + threadIdx.x;        // [0, 524288)
    int h = g & 1023;
    int b = (g >> 10) & 15;
    int j = g >> 14;
    const unsigned short* zp = zT + ((((size_t)((b << 10) | h)) << 10) + j * TC);
    const unsigned short* fp = zp + PLANE;
    short8 zv[4], fv[4];
#pragma unroll
    for (int q = 0; q < 4; ++q) {
        zv[q] = *(const short8*)(zp + q * 8);
        fv[q] = *(const short8*)(fp + q * 8);
    }
    float c = 0.f, pr = 1.f;
#pragma unroll
    for (int q = 0; q < 4; ++q)
#pragma unroll
        for (int k = 0; k < 8; ++k) {
            float z = bf2f((unsigned short)zv[q][k]);
            float f = bf2f((unsigned short)fv[q][k]);
            c = fmaf(f, c, (1.0f - f) * z);
            pr *= f;
        }
    int o = (j << 14) | (b << 10) | h;
    P[o] = pr;
    S[o] = c;
}

// Pass B: scan the 32 chunk summaries per chain; Cin[j] = cell state entering chunk j
__global__ __launch_bounds__(256) void scan_prefix_kernel(const float* __restrict__ P,
                                                          const float* __restrict__ S,
                                                          float* __restrict__ Cin) {
    int idx = blockIdx.x * 256 + threadIdx.x;      // [0, 16384) = (b,h)
    float c = 0.f;
#pragma unroll
    for (int j = 0; j < NCH; ++j) {
        int o = (j << 14) + idx;
        Cin[o] = c;
        c = fmaf(P[o], c, S[o]);
    }
}

// Pass C: redo local scan seeded with Cin, write c and h = o*c (coalesced fp32 stores)
__global__ __launch_bounds__(256) void scan_apply_kernel(const unsigned short* __restrict__ zT,
                                                         const float* __restrict__ Cin,
                                                         float* __restrict__ out) {
    int g = blockIdx.x * 256 + threadIdx.x;        // [0, 524288)
    int h = g & 1023;
    int b = (g >> 10) & 15;
    int j = g >> 14;
    const unsigned short* zp = zT + ((((size_t)((b << 10) | h)) << 10) + j * TC);
    const unsigned short* fp = zp + PLANE;
    const unsigned short* op = zp + 2 * (size_t)PLANE;
    short8 zv[4], fv[4], ov[4];
#pragma unroll
    for (int q = 0; q < 4; ++q) {
        zv[q] = *(const short8*)(zp + q * 8);
        fv[q] = *(const short8*)(fp + q * 8);
        ov[q] = *(const short8*)(op + q * 8);
    }
    float c = Cin[(j << 14) | (b << 10) | h];
    float* cbase = out + ((((size_t)((b << 10) | (j * TC))) << 10) | h);
#pragma unroll
    for (int q = 0; q < 4; ++q)
#pragma unroll
        for (int k = 0; k < 8; ++k) {
            float z = bf2f((unsigned short)zv[q][k]);
            float f = bf2f((unsigned short)fv[q][k]);
            float o = bf2f((unsigned short)ov[q][k]);
            c = fmaf(f, c, (1.0f - f) * z);
            float* cp = cbase + (((size_t)(q * 8 + k)) << 10);
            cp[0] = c;
            cp[(size_t)1 << 24] = o * c;           // h-plane offset = BB*TT*HH
        }
}

extern "C" void kernel_launch(void* const* d_in, const int* in_sizes, int n_in,
                              void* d_out, int out_size, void* d_ws, size_t ws_size,
                              hipStream_t stream) {
    const float* x    = (const float*)d_in[0];   // [B,T,D] fp32
    const float* w    = (const float*)d_in[1];   // [3H,D,2] fp32
    const float* bias = (const float*)d_in[2];   // [3H] fp32
    float* out = (float*)d_out;                  // [2, B, T, H] fp32 (c then h)

    char* ws = (char*)d_ws;
    const size_t xpad_bytes = (size_t)BB * TP * DD * 2;        // 33,587,200
    const size_t btw_bytes  = (size_t)NN * KK * 2;             // 12,582,912
    unsigned short* xpad = (unsigned short*)ws;
    unsigned short* Btw  = (unsigned short*)(ws + xpad_bytes);
    unsigned short* zT   = (unsigned short*)(ws + xpad_bytes + btw_bytes);   // [3][B][H][T]
    // scan scratch aliases the xpad region (dead after the GEMM): 3 x 2 MB
    float* P   = (float*)ws;
    float* S   = (float*)(ws + (size_t)MM * NCH * 4);
    float* Cin = (float*)(ws + (size_t)MM * NCH * 8);

    {
        int total = BB * TP * (DD / 4);
        pack_x_kernel<<<(total + 255) / 256, 256, 0, stream>>>(x, xpad);
    }
    {
        int total = NN * DD;
        pack_w_kernel<<<(total + 255) / 256, 256, 0, stream>>>(w, Btw);
    }
    {
        static int gemm_attr_done = 0;
        if (!gemm_attr_done) {
            (void)hipFuncSetAttribute((const void*)gemm_gates_kernel,
                                      hipFuncAttributeMaxDynamicSharedMemorySize, 131072);
            gemm_attr_done = 1;
        }
        dim3 grid(MM / 256, NN / 256);   // 64 x 12 = 768 blocks (3 full CU rounds)
        gemm_gates_kernel<<<grid, 512, 131072, stream>>>(xpad, Btw, bias, zT);
    }
    scan_summary_kernel<<<MM * NCH / 256, 256, 0, stream>>>(zT, P, S);
    scan_prefix_kernel<<<MM / 256, 256, 0, stream>>>(P, S, Cin);
    scan_apply_kernel<<<MM * NCH / 256, 256, 0, stream>>>(zT, Cin, out);
}

// Round 6
// 440.911 us; speedup vs baseline: 1.1275x; 1.0061x over previous
//
#include <hip/hip_runtime.h>

// Problem constants
#define BB 16
#define TT 1024
#define DD 1024
#define HH 1024
#define NN 3072            // 3H
#define KK 2048            // 2D (two conv taps)
#define MM (BB * TT)       // 16384
#define TP (TT + 1)        // padded time rows in xpad (row 0 = zeros)
#define NCH 128            // scan chunks
#define TC  8              // steps per chunk (NCH*TC == TT)
#define PLANE (1u << 24)   // 16M elements per gate plane ( = BB*HH*TT )

typedef __attribute__((ext_vector_type(8))) short short8;   // 8 x bf16
typedef __attribute__((ext_vector_type(4))) float float4v;  // MFMA acc

__device__ __forceinline__ unsigned short f2bf(float f) {
    unsigned int u = __float_as_uint(f);
    u += 0x7fffu + ((u >> 16) & 1u);   // round-to-nearest-even
    return (unsigned short)(u >> 16);
}
__device__ __forceinline__ float bf2f(unsigned short s) {
    return __uint_as_float(((unsigned int)s) << 16);
}

// async global->LDS, 16B per lane; LDS dest semantics: wave-uniform base + lane*16
__device__ __forceinline__ void gload_lds16(const unsigned short* g, unsigned short* l) {
    __builtin_amdgcn_global_load_lds(
        (const __attribute__((address_space(1))) unsigned int*)(g),
        (__attribute__((address_space(3))) unsigned int*)(l),
        16, 0, 0);
}

// ---------------- pack x: fp32 [B,T,D] -> bf16 xpad [B, T+1, D], row 0 zero ----------------
__global__ __launch_bounds__(256) void pack_x_kernel(const float* __restrict__ x,
                                                     unsigned short* __restrict__ xpad) {
    int i = blockIdx.x * 256 + threadIdx.x;          // one float4 group
    int total = BB * TP * (DD / 4);
    if (i >= total) return;
    int d4  = i & (DD / 4 - 1);
    int row = i >> 8;                                // [0, B*TP)
    int b  = row / TP;
    int tp = row - b * TP;
    float4 v = make_float4(0.f, 0.f, 0.f, 0.f);
    if (tp > 0)
        v = ((const float4*)x)[(((size_t)(b * TT + tp - 1)) << 8) + d4];
    ushort4 r4;
    r4.x = f2bf(v.x); r4.y = f2bf(v.y); r4.z = f2bf(v.z); r4.w = f2bf(v.w);
    *(ushort4*)(xpad + (((size_t)row) << 10) + (d4 << 2)) = r4;
}

// ---------------- pack w: fp32 [3H, D, 2] -> bf16 Bt [N=3072][K=2048] (B^T layout) ----------
__global__ __launch_bounds__(256) void pack_w_kernel(const float* __restrict__ w,
                                                     unsigned short* __restrict__ Bt) {
    int i = blockIdx.x * 256 + threadIdx.x;          // n*1024 + d
    if (i >= NN * DD) return;
    int n = i >> 10, d = i & 1023;
    float2 v = ((const float2*)w)[i];                // (w[n,d,0], w[n,d,1])
    Bt[(size_t)n * KK + d]       = f2bf(v.x);        // tap0 at k = d
    Bt[(size_t)n * KK + DD + d]  = f2bf(v.y);        // tap1 at k = 1024 + d
}

// ---------------- GEMM: gates = A * W^T, fused bias + activation ---------------------------
// 256x256 tile, BK=64, 512 threads (8 waves as 2M x 4N, 128x64 per wave).
// ONE barrier per K-tile (R2 structure — best measured: 48.6% MfmaUtil, 190.9us).
// Staging targets the other buffer and is issued right after the barrier -> full-tile
// prefetch lead, so the __syncthreads() vmcnt(0) drain is ~free. Compiler's fine-grained
// lgkmcnt + 2-waves/SIMD stagger overlap LDS service with MFMA.
// LDS chunk-swizzle: physical 16B chunk pc at row r holds logical chunk pc^(r&7); applied on
// the global SOURCE address (gload_lds writes linearly) and mirrored on ds_read addresses.
// Output layout: zT[gate][b][j8][h][8] bf16 — each 16B epilogue store is one (h,j8) cell,
// stored h-contiguously (consecutive lanes -> consecutive h) for full coalescing.

#define STAGE_TILE(ASN, BSN, KT) do {                                          \
    const int tap_ = (KT) >> 4;                                                \
    const size_t aoff_ = aSrc + (((size_t)tap_) << 10) + (((KT) & 15) << 6);   \
    const size_t boff_ = bSrc + (((size_t)(KT)) << 6);                         \
    gload_lds16(xpad + aoff_,                 (ASN) + ldsStage);               \
    gload_lds16(xpad + aoff_ + (64u << 10),   (ASN) + ldsStage + 4096);        \
    gload_lds16(xpad + aoff_ + (128u << 10),  (ASN) + ldsStage + 8192);        \
    gload_lds16(xpad + aoff_ + (192u << 10),  (ASN) + ldsStage + 12288);       \
    gload_lds16(Btw + boff_,                  (BSN) + ldsStage);               \
    gload_lds16(Btw + boff_ + (64u << 11),    (BSN) + ldsStage + 4096);        \
    gload_lds16(Btw + boff_ + (128u << 11),   (BSN) + ldsStage + 8192);        \
    gload_lds16(Btw + boff_ + (192u << 11),   (BSN) + ldsStage + 12288);       \
} while (0)

// one phase = one 32-row M-quadrant of the wave's 128x64 C, full K=64: 16 MFMA.
// k0 MFMAs first (8 independent accs), then k1 — no back-to-back same-acc dependency.
#define MFMA16(P, AA, AB, AC, AD) do {                                         \
    __builtin_amdgcn_s_setprio(1);                                             \
    acc[2*(P)  ][0] = __builtin_amdgcn_mfma_f32_16x16x32_bf16(AA, b00, acc[2*(P)  ][0], 0, 0, 0); \
    acc[2*(P)+1][0] = __builtin_amdgcn_mfma_f32_16x16x32_bf16(AB, b00, acc[2*(P)+1][0], 0, 0, 0); \
    acc[2*(P)  ][1] = __builtin_amdgcn_mfma_f32_16x16x32_bf16(AA, b10, acc[2*(P)  ][1], 0, 0, 0); \
    acc[2*(P)+1][1] = __builtin_amdgcn_mfma_f32_16x16x32_bf16(AB, b10, acc[2*(P)+1][1], 0, 0, 0); \
    acc[2*(P)  ][2] = __builtin_amdgcn_mfma_f32_16x16x32_bf16(AA, b20, acc[2*(P)  ][2], 0, 0, 0); \
    acc[2*(P)+1][2] = __builtin_amdgcn_mfma_f32_16x16x32_bf16(AB, b20, acc[2*(P)+1][2], 0, 0, 0); \
    acc[2*(P)  ][3] = __builtin_amdgcn_mfma_f32_16x16x32_bf16(AA, b30, acc[2*(P)  ][3], 0, 0, 0); \
    acc[2*(P)+1][3] = __builtin_amdgcn_mfma_f32_16x16x32_bf16(AB, b30, acc[2*(P)+1][3], 0, 0, 0); \
    acc[2*(P)  ][0] = __builtin_amdgcn_mfma_f32_16x16x32_bf16(AC, b01, acc[2*(P)  ][0], 0, 0, 0); \
    acc[2*(P)+1][0] = __builtin_amdgcn_mfma_f32_16x16x32_bf16(AD, b01, acc[2*(P)+1][0], 0, 0, 0); \
    acc[2*(P)  ][1] = __builtin_amdgcn_mfma_f32_16x16x32_bf16(AC, b11, acc[2*(P)  ][1], 0, 0, 0); \
    acc[2*(P)+1][1] = __builtin_amdgcn_mfma_f32_16x16x32_bf16(AD, b11, acc[2*(P)+1][1], 0, 0, 0); \
    acc[2*(P)  ][2] = __builtin_amdgcn_mfma_f32_16x16x32_bf16(AC, b21, acc[2*(P)  ][2], 0, 0, 0); \
    acc[2*(P)+1][2] = __builtin_amdgcn_mfma_f32_16x16x32_bf16(AD, b21, acc[2*(P)+1][2], 0, 0, 0); \
    acc[2*(P)  ][3] = __builtin_amdgcn_mfma_f32_16x16x32_bf16(AC, b31, acc[2*(P)  ][3], 0, 0, 0); \
    acc[2*(P)+1][3] = __builtin_amdgcn_mfma_f32_16x16x32_bf16(AD, b31, acc[2*(P)+1][3], 0, 0, 0); \
    __builtin_amdgcn_s_setprio(0);                                             \
} while (0)

#define TILE(ASC, BSC, ASN, BSN, KTN, DOSTAGE) do {                            \
    const unsigned short* aP_ = (ASC) + aRowRd;                                \
    const unsigned short* bP_ = (BSC) + bRowRd;                                \
    short8 b00 = *(const short8*)(bP_ +    0 + pch0);                          \
    short8 b10 = *(const short8*)(bP_ + 1024 + pch0);                          \
    short8 b20 = *(const short8*)(bP_ + 2048 + pch0);                          \
    short8 b30 = *(const short8*)(bP_ + 3072 + pch0);                          \
    short8 aAx = *(const short8*)(aP_ +    0 + pch0);                          \
    short8 aBx = *(const short8*)(aP_ + 1024 + pch0);                          \
    short8 b01 = *(const short8*)(bP_ +    0 + pch1);                          \
    short8 b11 = *(const short8*)(bP_ + 1024 + pch1);                          \
    short8 b21 = *(const short8*)(bP_ + 2048 + pch1);                          \
    short8 b31 = *(const short8*)(bP_ + 3072 + pch1);                          \
    short8 aCx = *(const short8*)(aP_ +    0 + pch1);                          \
    short8 aDx = *(const short8*)(aP_ + 1024 + pch1);                          \
    if (DOSTAGE) { STAGE_TILE(ASN, BSN, KTN); }                                \
    MFMA16(0, aAx, aBx, aCx, aDx);                                             \
    aAx = *(const short8*)(aP_ + 2048 + pch0);                                 \
    aBx = *(const short8*)(aP_ + 3072 + pch0);                                 \
    aCx = *(const short8*)(aP_ + 2048 + pch1);                                 \
    aDx = *(const short8*)(aP_ + 3072 + pch1);                                 \
    MFMA16(1, aAx, aBx, aCx, aDx);                                             \
    aAx = *(const short8*)(aP_ + 4096 + pch0);                                 \
    aBx = *(const short8*)(aP_ + 5120 + pch0);                                 \
    aCx = *(const short8*)(aP_ + 4096 + pch1);                                 \
    aDx = *(const short8*)(aP_ + 5120 + pch1);                                 \
    MFMA16(2, aAx, aBx, aCx, aDx);                                             \
    aAx = *(const short8*)(aP_ + 6144 + pch0);                                 \
    aBx = *(const short8*)(aP_ + 7168 + pch0);                                 \
    aCx = *(const short8*)(aP_ + 6144 + pch1);                                 \
    aDx = *(const short8*)(aP_ + 7168 + pch1);                                 \
    MFMA16(3, aAx, aBx, aCx, aDx);                                             \
    __syncthreads();                                                           \
} while (0)

__global__ __launch_bounds__(512, 2) void gemm_gates_kernel(const unsigned short* __restrict__ xpad,
                                                            const unsigned short* __restrict__ Btw,
                                                            const float* __restrict__ bias,
                                                            unsigned short* __restrict__ zT) {
    extern __shared__ unsigned short lds[];          // 131072 B
    unsigned short* As0 = lds;                       // [256][64] bf16, swizzled chunks
    unsigned short* As1 = lds + 16384;
    unsigned short* Bs0 = lds + 32768;
    unsigned short* Bs1 = lds + 49152;

    const int tid  = threadIdx.x;
    const int lane = tid & 63;
    const int w    = tid >> 6;
    const int wm   = w >> 2;                         // 0..1 (M)
    const int wn   = w & 3;                          // 0..3 (N)
    const int mrow = lane & 15;
    const int quad = lane >> 4;

    const int m0 = blockIdx.x << 8;
    const int n0 = blockIdx.y << 8;
    const int bidx = m0 >> 10;                       // 256 | 1024: tile never straddles batch
    const int t0   = m0 & 1023;

    // staging precomputes: per gload call thread covers (row = r0 + tid>>3, chunk = tid&7)
    const int rr  = tid >> 3;
    const int cc8 = (((tid & 7) ^ (rr & 7)) << 3);   // pre-swizzled source chunk
    const size_t aSrc = (((size_t)(bidx * TP + t0 + rr)) << 10) + cc8;
    const size_t bSrc = (((size_t)(n0 + rr)) << 11) + cc8;
    const int ldsStage = (rr << 6) + ((tid & 7) << 3);   // linear LDS dest (lane*16B per wave)

    // fragment-read precomputes (row&7 == lane&7 for all frag rows)
    const int pch0 = ((quad ^ (lane & 7)) << 3);         // k-slice 0, swizzled chunk
    const int pch1 = (((4 | quad) ^ (lane & 7)) << 3);   // k-slice 1
    const int aRowRd = ((wm << 7) + mrow) << 6;
    const int bRowRd = ((wn << 6) + mrow) << 6;

    float4v acc[8][4];
#pragma unroll
    for (int i = 0; i < 8; ++i)
#pragma unroll
        for (int j = 0; j < 4; ++j) acc[i][j] = (float4v)0.0f;

    // prologue: stage K-tile 0, drain once (inside __syncthreads), go
    STAGE_TILE(As0, Bs0, 0);
    __syncthreads();

#pragma unroll 1
    for (int jt = 0; jt < 30; jt += 2) {
        TILE(As0, Bs0, As1, Bs1, jt + 1, 1);
        TILE(As1, Bs1, As0, Bs0, jt + 2, 1);
    }
    TILE(As0, Bs0, As1, Bs1, 31, 1);                 // tile 30, stage 31
    TILE(As1, Bs1, As0, Bs0, 0, 0);                  // tile 31, no stage

    // ---------------- epilogue: bias + activation + LDS transpose + coalesced store --------
    unsigned short* Ts = lds;                        // [256 n][256 t] bf16, chunk-XOR swizzled
    const bool isZ = (n0 < HH);
    float bv[4];
#pragma unroll
    for (int ng = 0; ng < 4; ++ng) bv[ng] = bias[n0 + (wn << 6) + (ng << 4) + mrow];

#pragma unroll
    for (int g = 0; g < 8; ++g) {
#pragma unroll
        for (int ng = 0; ng < 4; ++ng) {
            const int nloc = (wn << 6) + (ng << 4) + mrow;          // tile row (n-local)
            const int m0l  = (wm << 7) + (g << 4) + (quad << 2);    // tile col (t-local), 4 consec
            float v0 = acc[g][ng][0] + bv[ng];
            float v1 = acc[g][ng][1] + bv[ng];
            float v2 = acc[g][ng][2] + bv[ng];
            float v3 = acc[g][ng][3] + bv[ng];
            float g0, g1, g2, g3;
            if (isZ) {
                g0 = 2.0f * __builtin_amdgcn_rcpf(1.0f + __expf(-2.0f * v0)) - 1.0f;
                g1 = 2.0f * __builtin_amdgcn_rcpf(1.0f + __expf(-2.0f * v1)) - 1.0f;
                g2 = 2.0f * __builtin_amdgcn_rcpf(1.0f + __expf(-2.0f * v2)) - 1.0f;
                g3 = 2.0f * __builtin_amdgcn_rcpf(1.0f + __expf(-2.0f * v3)) - 1.0f;
            } else {
                g0 = __builtin_amdgcn_rcpf(1.0f + __expf(-v0));
                g1 = __builtin_amdgcn_rcpf(1.0f + __expf(-v1));
                g2 = __builtin_amdgcn_rcpf(1.0f + __expf(-v2));
                g3 = __builtin_amdgcn_rcpf(1.0f + __expf(-v3));
            }
            unsigned int d0 = (unsigned int)f2bf(g0) | ((unsigned int)f2bf(g1) << 16);
            unsigned int d1 = (unsigned int)f2bf(g2) | ((unsigned int)f2bf(g3) << 16);
            const int chunk = (m0l >> 3) ^ (nloc & 31);             // 16B-chunk XOR swizzle
            *(uint2*)(Ts + nloc * 256 + (chunk << 3) + (m0l & 7)) = make_uint2(d0, d1);
        }
    }
    __syncthreads();

    // store: each lane's 16B = one (h, j8) cell of zT[gate][b][j8][h][8].
    // consecutive lanes -> consecutive h  =>  4KB contiguous per 256-lane group.
    const int gate = n0 >> 10;
    unsigned short* plane = zT + ((size_t)gate << 24);
    const int hl = tid & 255;                        // h-local (contiguous across lanes)
    const int jw = tid >> 8;                         // 0..1
    const int j80 = t0 >> 3;                         // tile covers j8 = j80 .. j80+31
#pragma unroll
    for (int p = 0; p < 16; ++p) {
        const int j8l = (p << 1) + jw;               // t-chunk local 0..31
        const int chunk = j8l ^ (hl & 31);           // Ts swizzle for t-local block j8l
        short8 vv = *(const short8*)(Ts + hl * 256 + (chunk << 3));
        const int h = (n0 & 1023) + hl;
        const size_t dst = ((((size_t)((bidx << 7) | (j80 + j8l))) << 10 | (unsigned)h) << 3);
        *(short8*)(plane + dst) = vv;
    }
}

// ---------------- chunked fo-pooling scan, 3 passes ----------------------------------------
// zT layout: [gate][b][j][h][8] — thread g: h = g&1023, j = (g>>10)&127, b = g>>17.
// Lane's 16B load = its whole chunk; consecutive lanes = consecutive h = contiguous 1KB/wave.
// Summaries at o = (j<<14) | (b<<10) | h.

// Pass A: per-chunk summaries P = prod f, S = local scan from 0
__global__ __launch_bounds__(256) void scan_summary_kernel(const unsigned short* __restrict__ zT,
                                                           float* __restrict__ P,
                                                           float* __restrict__ S) {
    int g = blockIdx.x * 256 + threadIdx.x;        // [0, 2097152)
    const unsigned short* zp = zT + ((size_t)g << 3);
    const unsigned short* fp = zp + PLANE;
    short8 zv = *(const short8*)zp;
    short8 fv = *(const short8*)fp;
    float c = 0.f, pr = 1.f;
#pragma unroll
    for (int k = 0; k < 8; ++k) {
        float z = bf2f((unsigned short)zv[k]);
        float f = bf2f((unsigned short)fv[k]);
        c = fmaf(f, c, (1.0f - f) * z);
        pr *= f;
    }
    int h = g & 1023, j = (g >> 10) & 127, b = g >> 17;
    int o = (j << 14) | (b << 10) | h;
    P[o] = pr;
    S[o] = c;
}

// Pass B: parallel affine scan of 128 chunk summaries per chain (2 chains per block).
// T_j(c) = p_j*c + s_j; inclusive composition via shfl Hillis-Steele + cross-wave LDS fix.
__global__ __launch_bounds__(256) void scan_prefix_kernel(const float* __restrict__ P,
                                                          const float* __restrict__ S,
                                                          float* __restrict__ Cin) {
    __shared__ float totP[4], totS[4], incl[256];
    const int tid  = threadIdx.x;
    const int j    = tid & 127;
    const int cL   = tid >> 7;                      // chain-local 0..1
    const int idx  = blockIdx.x * 2 + cL;           // (b<<10)|h
    const int o    = (j << 14) + idx;
    const int lane = tid & 63;
    const int wid  = tid >> 6;

    float p = P[o], s = S[o];
#pragma unroll
    for (int d = 1; d < 64; d <<= 1) {
        float ps = __shfl_up(p, d, 64);
        float ss = __shfl_up(s, d, 64);
        if (lane >= d) { s = fmaf(p, ss, s); p = p * ps; }
    }
    if (lane == 63) { totP[wid] = p; totS[wid] = s; }
    __syncthreads();
    if (wid & 1) {                                  // second wave of each chain
        float ss = totS[wid - 1];
        s = fmaf(p, ss, s);
    }
    incl[tid] = s;                                  // inclusive cell state after chunk j (c0=0)
    __syncthreads();
    Cin[o] = (j == 0) ? 0.f : incl[tid - 1];
}

// Pass C: redo local scan seeded with Cin, write c and h = o*c (coalesced fp32 stores)
__global__ __launch_bounds__(256) void scan_apply_kernel(const unsigned short* __restrict__ zT,
                                                         const float* __restrict__ Cin,
                                                         float* __restrict__ out) {
    int g = blockIdx.x * 256 + threadIdx.x;        // [0, 2097152)
    const unsigned short* zp = zT + ((size_t)g << 3);
    const unsigned short* fp = zp + PLANE;
    const unsigned short* op = zp + 2 * (size_t)PLANE;
    short8 zv = *(const short8*)zp;
    short8 fv = *(const short8*)fp;
    short8 ov = *(const short8*)op;
    int h = g & 1023, j = (g >> 10) & 127, b = g >> 17;
    float c = Cin[(j << 14) | (b << 10) | h];
    float* cbase = out + ((((size_t)((b << 10) | (j * TC))) << 10) | h);
#pragma unroll
    for (int k = 0; k < 8; ++k) {
        float z = bf2f((unsigned short)zv[k]);
        float f = bf2f((unsigned short)fv[k]);
        float o = bf2f((unsigned short)ov[k]);
        c = fmaf(f, c, (1.0f - f) * z);
        float* cp = cbase + (((size_t)k) << 10);
        cp[0] = c;
        cp[(size_t)1 << 24] = o * c;               // h-plane offset = BB*TT*HH
    }
}

extern "C" void kernel_launch(void* const* d_in, const int* in_sizes, int n_in,
                              void* d_out, int out_size, void* d_ws, size_t ws_size,
                              hipStream_t stream) {
    const float* x    = (const float*)d_in[0];   // [B,T,D] fp32
    const float* w    = (const float*)d_in[1];   // [3H,D,2] fp32
    const float* bias = (const float*)d_in[2];   // [3H] fp32
    float* out = (float*)d_out;                  // [2, B, T, H] fp32 (c then h)

    char* ws = (char*)d_ws;
    const size_t xpad_bytes = (size_t)BB * TP * DD * 2;        // 33,587,200
    const size_t btw_bytes  = (size_t)NN * KK * 2;             // 12,582,912
    unsigned short* xpad = (unsigned short*)ws;
    unsigned short* Btw  = (unsigned short*)(ws + xpad_bytes);
    unsigned short* zT   = (unsigned short*)(ws + xpad_bytes + btw_bytes);   // [3][B][j][h][8]
    // scan scratch aliases the xpad region (dead after the GEMM): 3 x 8 MB
    float* P   = (float*)ws;
    float* S   = (float*)(ws + (size_t)MM * NCH * 4);
    float* Cin = (float*)(ws + (size_t)MM * NCH * 8);

    {
        int total = BB * TP * (DD / 4);
        pack_x_kernel<<<(total + 255) / 256, 256, 0, stream>>>(x, xpad);
    }
    {
        int total = NN * DD;
        pack_w_kernel<<<(total + 255) / 256, 256, 0, stream>>>(w, Btw);
    }
    {
        static int gemm_attr_done = 0;
        if (!gemm_attr_done) {
            (void)hipFuncSetAttribute((const void*)gemm_gates_kernel,
                                      hipFuncAttributeMaxDynamicSharedMemorySize, 131072);
            gemm_attr_done = 1;
        }
        dim3 grid(MM / 256, NN / 256);   // 64 x 12 = 768 blocks (3 full CU rounds)
        gemm_gates_kernel<<<grid, 512, 131072, stream>>>(xpad, Btw, bias, zT);
    }
    scan_summary_kernel<<<MM * NCH / 256, 256, 0, stream>>>(zT, P, S);
    scan_prefix_kernel<<<MM / 2, 256, 0, stream>>>(P, S, Cin);
    scan_apply_kernel<<<MM * NCH / 256, 256, 0, stream>>>(zT, Cin, out);
}